// Round 4
// baseline (411.371 us; speedup 1.0000x reference)
//
#include <hip/hip_runtime.h>
#include <cstdint>

// MoE: B=16384 rows, D=2048 feat, E=16 experts, C=64 classes/expert.
// All math fp32 (argmax outputs can't tolerate bf16 error vs np reference).
// R4: (a) coarse path fused to ONE kernel (wave-per-4-rows, 16 accs/lane,
// split-shuffle reduction, fused argmax+compaction+schedule-build via
// last-block done-counter) — kills coarse split-K partial traffic + 2
// dispatches. (b) expert GEMM KCH 32->64: 8 barrier-pairs/block not 16.
static constexpr int B_ = 16384;
static constexpr int D_ = 2048;
static constexpr int E_ = 16;
static constexpr int C_ = 64;
static constexpr int TR_E = 64;    // expert tile rows
static constexpr int SK_E = 4;     // expert split-K
static constexpr int KCH_E = 64;   // expert K-chunk in LDS
static constexpr int MAXITEMS = (B_ / TR_E) + E_;  // 272 worst case

// ---------------- fused coarse router ----------------
// Each wave: 4 rows. Lane covers K = {lane*4 + 256*c}. acc[4][16] in regs.
// Weights (128 KB) stay L1/L2-hot across waves. Reduction: split-halves
// shuffle (17 shfl/row) -> lane holds expert bitrev4(lane&15)'s total.
__global__ __launch_bounds__(256) void coarse_fused(
    const float* __restrict__ feat, const float* __restrict__ cw,
    const float* __restrict__ cb, float* __restrict__ out0,
    float* __restrict__ out1, int* __restrict__ eidArr, int* __restrict__ cnt,
    int* __restrict__ done, int* __restrict__ rowList,
    int* __restrict__ sched, int* __restrict__ nItems) {
  __shared__ int lcnt[E_];
  __shared__ int lbase[E_];
  __shared__ int rowE[16];
  __shared__ int rowP[16];
  __shared__ int lastFlag;

  const int tid = threadIdx.x;
  const int lane = tid & 63;
  const int wv = tid >> 6;
  if (tid < E_) lcnt[tid] = 0;
  if (tid == 0) lastFlag = 0;
  __syncthreads();

  const int rowBase = blockIdx.x * 16 + wv * 4;
  // expert owned by this lane after the split-reduction
  const int le = ((lane & 1) << 3) | ((lane & 2) << 1) | ((lane & 4) >> 1) |
                 ((lane & 8) >> 3);
  const float cbr = cb[le];

  const float* rp[4];
#pragma unroll
  for (int r = 0; r < 4; ++r)
    rp[r] = feat + (size_t)(rowBase + r) * D_ + lane * 4;

  float acc[4][16];
#pragma unroll
  for (int r = 0; r < 4; ++r)
#pragma unroll
    for (int j = 0; j < 16; ++j) acc[r][j] = 0.f;

  float4 pf[4];
#pragma unroll
  for (int r = 0; r < 4; ++r) pf[r] = *(const float4*)(rp[r]);

  for (int c = 0; c < 8; ++c) {  // 8 chunks of 256 K each
    float4 f[4];
#pragma unroll
    for (int r = 0; r < 4; ++r) f[r] = pf[r];
    if (c < 7) {
#pragma unroll
      for (int r = 0; r < 4; ++r)
        pf[r] = *(const float4*)(rp[r] + (c + 1) * 256);
    }
    const float* wb = cw + c * 256 + lane * 4;
#pragma unroll
    for (int e4 = 0; e4 < 4; ++e4) {
      float4 w[4];
#pragma unroll
      for (int j = 0; j < 4; ++j)
        w[j] = *(const float4*)(wb + (size_t)(e4 * 4 + j) * D_);
#pragma unroll
      for (int j = 0; j < 4; ++j)
#pragma unroll
        for (int r = 0; r < 4; ++r) {
          acc[r][e4 * 4 + j] += f[r].x * w[j].x;
          acc[r][e4 * 4 + j] += f[r].y * w[j].y;
          acc[r][e4 * 4 + j] += f[r].z * w[j].z;
          acc[r][e4 * 4 + j] += f[r].w * w[j].w;
        }
    }
  }

  // per-row: reduce 16 accs across 64 lanes, bias, write, argmax, compaction
#pragma unroll
  for (int r = 0; r < 4; ++r) {
    float v[16];
#pragma unroll
    for (int j = 0; j < 16; ++j) v[j] = acc[r][j];
    {  // d=1: keep 8 (hi lanes keep experts 8-15)
      const bool hi = lane & 1;
#pragma unroll
      for (int j = 0; j < 8; ++j) {
        const float a = v[j], b = v[j + 8];
        v[j] = hi ? b : a;
        v[j + 8] = hi ? a : b;
      }
#pragma unroll
      for (int j = 0; j < 8; ++j) v[j] += __shfl_xor(v[j + 8], 1);
    }
    {  // d=2
      const bool hi = lane & 2;
#pragma unroll
      for (int j = 0; j < 4; ++j) {
        const float a = v[j], b = v[j + 4];
        v[j] = hi ? b : a;
        v[j + 4] = hi ? a : b;
      }
#pragma unroll
      for (int j = 0; j < 4; ++j) v[j] += __shfl_xor(v[j + 4], 2);
    }
    {  // d=4
      const bool hi = lane & 4;
#pragma unroll
      for (int j = 0; j < 2; ++j) {
        const float a = v[j], b = v[j + 2];
        v[j] = hi ? b : a;
        v[j + 2] = hi ? a : b;
      }
#pragma unroll
      for (int j = 0; j < 2; ++j) v[j] += __shfl_xor(v[j + 2], 4);
    }
    {  // d=8
      const bool hi = lane & 8;
      const float a = v[0], b = v[1];
      v[0] = hi ? b : a;
      v[1] = hi ? a : b;
      v[0] += __shfl_xor(v[1], 8);
    }
    v[0] += __shfl_xor(v[0], 16);
    v[0] += __shfl_xor(v[0], 32);
    const float val = v[0] + cbr;

    const int row = rowBase + r;
    if (lane < 16) out0[(size_t)row * E_ + le] = val;

    // argmax over the 16 experts (each 16-lane group identical)
    float mv = val;
    int mi = le;
#pragma unroll
    for (int d = 1; d <= 8; d <<= 1) {
      const float ov = __shfl_xor(mv, d);
      const int oi = __shfl_xor(mi, d);
      if (ov > mv || (ov == mv && oi < mi)) {
        mv = ov;
        mi = oi;
      }
    }
    if (lane == 0) {
      out1[row] = (float)mi;
      eidArr[row] = mi;
      const int p = atomicAdd(&lcnt[mi], 1);
      rowE[wv * 4 + r] = mi;
      rowP[wv * 4 + r] = p;
    }
  }
  __syncthreads();
  if (tid < E_) lbase[tid] = atomicAdd(&cnt[tid], lcnt[tid]);
  __syncthreads();
  if (tid < 16) {
    const int e = rowE[tid], p = rowP[tid];
    rowList[e * B_ + lbase[e] + p] = blockIdx.x * 16 + tid;
  }

  // last block builds the expert-GEMM schedule (device atomics => visible)
  __threadfence();
  if (tid == 0) {
    if (atomicAdd(done, 1) == (int)gridDim.x - 1) lastFlag = 1;
  }
  __syncthreads();
  if (lastFlag) {
    if (tid < E_) lcnt[tid] = (atomicAdd(&cnt[tid], 0) + TR_E - 1) / TR_E;
    __syncthreads();
    if (tid == 0) {
      int a = 0;
      for (int e = 0; e < E_; ++e) {
        lbase[e] = a;
        a += lcnt[e];
      }
      *nItems = a;
    }
    __syncthreads();
    if (tid < E_) {
      const int o = lbase[tid], n = lcnt[tid];
      for (int k = 0; k < n; ++k) sched[o + k] = tid | (k << 8);
    }
  }
}

// ---------------- expert GEMM (flat schedule, split-K) ----------------
// part[kz][row][c] = sum_{kz K-range} feat[grow][d]*W[c][d].  W: [NC][D_].
// Feature/weight tiles transposed in LDS with XOR swizzle. KCH=64: 8
// barrier-pairs per block; LDS 32.25 KB -> 4 blocks/CU (16 waves).
template <int RPT, int CPT, int NC, int TR, int SK, int KCH>
__global__ __launch_bounds__(256) void gemm_expert(
    const float* __restrict__ feat, const float* __restrict__ Wall,
    const int* __restrict__ rowList, const int* __restrict__ cnt,
    const int* __restrict__ sched, const int* __restrict__ nItems,
    float* __restrict__ part0, float* __restrict__ partRest) {
  constexpr int DCB = KCH / 4;            // float4 chunks per row of a tile
  constexpr int FITER = TR * DCB / 256;   // feature float4 loads/thread/chunk
  constexpr int WSLOTS = NC * DCB;
  constexpr int WITER = (WSLOTS + 255) / 256;
  constexpr int CG = NC / CPT;
  constexpr int RB = TR / 8;              // row swizzle blocks
  constexpr int CB = NC / 8;

  __shared__ float fT[KCH * TR];
  __shared__ float wT[KCH * NC];
  __shared__ int rIdx[TR];

  const int tid = threadIdx.x;
  const int b = blockIdx.x;
  const int kz = b % SK;
  const int item = b / SK;
  if (item >= *nItems) return;
  const int s = sched[item];
  const int e = s & 255;
  const int tile = s >> 8;
  const int count = cnt[e];

  if (tid < TR) {
    const int slot = tile * TR + tid;
    rIdx[tid] = (slot < count) ? rowList[e * B_ + slot] : 0;
  }
  __syncthreads();

  unsigned grows[FITER];
  int dcf[FITER], sbf[FITER];
#pragma unroll
  for (int i = 0; i < FITER; ++i) {
    const int idx = i * 256 + tid;
    const int rl = idx / DCB;
    dcf[i] = idx % DCB;
    grows[i] = (unsigned)rIdx[rl];
    sbf[i] = (((rl >> 3) ^ (dcf[i] & (RB - 1))) << 3) + (rl & 7);
  }
  int wc[WITER], wdc[WITER], wsb[WITER];
#pragma unroll
  for (int i = 0; i < WITER; ++i) {
    const int idx = i * 256 + tid;
    const int c = idx / DCB;
    wc[i] = c;
    wdc[i] = idx % DCB;
    wsb[i] = (((c >> 3) ^ (wdc[i] & (CB - 1))) << 3) + (c & 7);
  }

  const int cg = tid % CG;
  const int rg = tid / CG;

  float acc[RPT][CPT];
#pragma unroll
  for (int r = 0; r < RPT; ++r)
#pragma unroll
    for (int c = 0; c < CPT; ++c) acc[r][c] = 0.f;

  const float* We = Wall + (size_t)e * NC * D_;
  constexpr int KRANGE = D_ / SK;
  constexpr int NCH = KRANGE / KCH;
  const int k0 = kz * KRANGE;

  float4 pf[FITER], pw[WITER];
#pragma unroll
  for (int i = 0; i < FITER; ++i)
    pf[i] = *(const float4*)(feat + (size_t)grows[i] * D_ + k0 + dcf[i] * 4);
#pragma unroll
  for (int i = 0; i < WITER; ++i)
    pw[i] = *(const float4*)(We + (size_t)wc[i] * D_ + k0 + wdc[i] * 4);

  for (int ch = 0; ch < NCH; ++ch) {
#pragma unroll
    for (int i = 0; i < FITER; ++i) {
      float* p = &fT[(dcf[i] * 4) * TR + sbf[i]];
      p[0 * TR] = pf[i].x;
      p[1 * TR] = pf[i].y;
      p[2 * TR] = pf[i].z;
      p[3 * TR] = pf[i].w;
    }
#pragma unroll
    for (int i = 0; i < WITER; ++i) {
      float* p = &wT[(wdc[i] * 4) * NC + wsb[i]];
      p[0 * NC] = pw[i].x;
      p[1 * NC] = pw[i].y;
      p[2 * NC] = pw[i].z;
      p[3 * NC] = pw[i].w;
    }
    __syncthreads();
    if (ch + 1 < NCH) {
      const int kb = k0 + (ch + 1) * KCH;
#pragma unroll
      for (int i = 0; i < FITER; ++i)
        pf[i] = *(const float4*)(feat + (size_t)grows[i] * D_ + kb + dcf[i] * 4);
#pragma unroll
      for (int i = 0; i < WITER; ++i)
        pw[i] = *(const float4*)(We + (size_t)wc[i] * D_ + kb + wdc[i] * 4);
    }
#pragma unroll
    for (int dd = 0; dd < KCH; ++dd) {
      const int sz = (dd >> 2) & (RB - 1);
      const int sw = (dd >> 2) & (CB - 1);
      float a[RPT], bb[CPT];
#pragma unroll
      for (int r4 = 0; r4 < RPT / 4; ++r4) {
        const int col = rg * RPT + r4 * 4;
        const float4 v =
            *(const float4*)&fT[dd * TR + (((col >> 3) ^ sz) << 3) + (col & 7)];
        a[r4 * 4 + 0] = v.x;
        a[r4 * 4 + 1] = v.y;
        a[r4 * 4 + 2] = v.z;
        a[r4 * 4 + 3] = v.w;
      }
#pragma unroll
      for (int c4 = 0; c4 < CPT / 4; ++c4) {
        const int col = cg * CPT + c4 * 4;
        const float4 v =
            *(const float4*)&wT[dd * NC + (((col >> 3) ^ sw) << 3) + (col & 7)];
        bb[c4 * 4 + 0] = v.x;
        bb[c4 * 4 + 1] = v.y;
        bb[c4 * 4 + 2] = v.z;
        bb[c4 * 4 + 3] = v.w;
      }
#pragma unroll
      for (int r = 0; r < RPT; ++r)
#pragma unroll
        for (int c = 0; c < CPT; ++c) acc[r][c] += a[r] * bb[c];
    }
    __syncthreads();
  }

  float* pk = kz ? (partRest + (size_t)(kz - 1) * B_ * NC) : part0;
#pragma unroll
  for (int r = 0; r < RPT; ++r) {
    const int lrow = rg * RPT + r;
    const int slot = tile * TR + lrow;
    if (slot < count) {
      const int grow = rIdx[lrow];
      float* dst = pk + (size_t)grow * NC + cg * CPT;
#pragma unroll
      for (int c4 = 0; c4 < CPT / 4; ++c4)
        *(float4*)(dst + c4 * 4) =
            make_float4(acc[r][c4 * 4 + 0], acc[r][c4 * 4 + 1],
                        acc[r][c4 * 4 + 2], acc[r][c4 * 4 + 3]);
    }
  }
}

// Wave-per-row: reduce y partials (fixed order), bias, softmax, argmax+start.
__global__ __launch_bounds__(256) void finish_rows(
    const float* __restrict__ ypart0, const float* __restrict__ ypartRest,
    const float* __restrict__ eb, const int* __restrict__ eidArr,
    float* __restrict__ out2, float* __restrict__ out3) {
  const int lane = threadIdx.x & 63;
  const int row = (blockIdx.x * 256 + threadIdx.x) >> 6;
  const int eid = eidArr[row];

  float v = eb[eid * C_ + lane];
  v += ypart0[(size_t)row * C_ + lane];
#pragma unroll
  for (int kz = 1; kz < SK_E; ++kz)
    v += ypartRest[((size_t)(kz - 1) * B_ + row) * C_ + lane];

  float m = v;
#pragma unroll
  for (int off = 32; off; off >>= 1) m = fmaxf(m, __shfl_xor(m, off));
  const float p = __expf(v - m);
  float s = p;
#pragma unroll
  for (int off = 32; off; off >>= 1) s += __shfl_xor(s, off);
  out2[(size_t)row * C_ + lane] = p / s;  // ypart0 aliases out2; read done

  float av = v;
  int ai = lane;
#pragma unroll
  for (int off = 32; off; off >>= 1) {
    const float ov = __shfl_xor(av, off);
    const int oi = __shfl_xor(ai, off);
    if (ov > av || (ov == av && oi < ai)) {
      av = ov;
      ai = oi;
    }
  }
  if (lane == 0) out3[row] = (float)(ai + (eid << 6));
}

extern "C" void kernel_launch(void* const* d_in, const int* in_sizes, int n_in,
                              void* d_out, int out_size, void* d_ws,
                              size_t ws_size, hipStream_t stream) {
  const float* feat = (const float*)d_in[0];  // [B, D]
  const float* cw = (const float*)d_in[1];    // [E, D]
  const float* cb = (const float*)d_in[2];    // [E]
  const float* ew = (const float*)d_in[3];    // [E, C, D]
  const float* eb = (const float*)d_in[4];    // [E, C]

  float* out0 = (float*)d_out;           // coarse_output [B, E]
  float* out1 = out0 + (size_t)B_ * E_;  // expert_id [B] (as float)
  float* out2 = out1 + B_;               // local_preds [B, C]
  float* out3 = out2 + (size_t)B_ * C_;  // global_preds [B]

  // ws (~13.7 MB): expert kz>=1 partials + routing metadata. kz==0 slice
  // aliases out2 (same element, same reducing thread).
  char* ws = (char*)d_ws;
  float* ypartRest = (float*)ws;                                   // 3*B*C
  int* rowList = (int*)(ypartRest + (size_t)(SK_E - 1) * B_ * C_);  // E*B
  int* cnt = rowList + (size_t)E_ * B_;  // 16 counts + done @ [16] (pad 64)
  int* done = cnt + E_;
  int* eidArr = cnt + 64;                // B
  int* sched = eidArr + B_;              // MAXITEMS (pad 512)
  int* nItems = sched + 512;             // 1

  hipMemsetAsync(cnt, 0, 256, stream);  // cnt[0..15] + done

  // 1) fused coarse: GEMM + argmax + compaction + schedule build
  coarse_fused<<<B_ / 16, 256, 0, stream>>>(feat, cw, cb, out0, out1, eidArr,
                                            cnt, done, rowList, sched, nItems);
  // 2) expert GEMM over dense flat-scheduled grid
  gemm_expert<4, 4, C_, TR_E, SK_E, KCH_E>
      <<<MAXITEMS * SK_E, 256, 0, stream>>>(feat, ew, rowList, cnt, sched,
                                            nItems, out2, ypartRest);
  // 3) softmax + argmax + class-range start
  finish_rows<<<(B_ * 64) / 256, 256, 0, stream>>>(out2, ypartRest, eb, eidArr,
                                                   out2, out3);
}

// Round 5
// 317.276 us; speedup vs baseline: 1.2966x; 1.2966x over previous
//
#include <hip/hip_runtime.h>
#include <cstdint>

// MoE: B=16384 rows, D=2048 feat, E=16 experts, C=64 classes/expert.
// All math fp32 (argmax outputs can't tolerate bf16 error vs np reference).
// R5: revert R4's latency-trap coarse_fused (per-wave L2 weight re-reads, 8%
// VALU, 177us). Coarse = LDS-tiled GEMM at 100% occupancy (TR=64,SK=8 ->
// 2048 blocks, 10.5KB LDS). Schedule build folded into coarse_finish's last
// block (one fewer dispatch). Expert GEMM: R3 shape + KCH=64 (8 barrier
// pairs/block instead of 16).
static constexpr int B_ = 16384;
static constexpr int D_ = 2048;
static constexpr int E_ = 16;
static constexpr int C_ = 64;
static constexpr int TR_E = 64;   // expert tile rows
static constexpr int SK_E = 4;    // expert split-K
static constexpr int TR_C = 64;   // coarse tile rows
static constexpr int SK_C = 8;    // coarse split-K
static constexpr int MAXITEMS = (B_ / TR_E) + E_;  // 272 worst case

// part[kz][row][c] = sum_{kz K-range} feat[grow][d]*W[c][d].  W: [NC][D_].
// Tiles transposed in LDS [dd][row] with XOR swizzle (<=2-way aliasing, free
// per m136). FLAT: dense worker ids from device-built (e,tile) schedule.
template <int RPT, int CPT, int NC, int TR, int SK, int KCH, bool FLAT>
__global__ __launch_bounds__(256) void gemm_tile(
    const float* __restrict__ feat, const float* __restrict__ Wall,
    const int* __restrict__ rowList, const int* __restrict__ cnt,
    const int* __restrict__ sched, const int* __restrict__ nItems,
    float* __restrict__ part0,      // kz==0 slice (aliased onto d_out region)
    float* __restrict__ partRest)   // kz>=1 slices in ws
{
  constexpr int DCB = KCH / 4;           // float4 slots per tile row
  constexpr int FITER = TR * DCB / 256;  // feature float4 loads/thread/chunk
  constexpr int WSLOTS = NC * DCB;
  constexpr int WITER = (WSLOTS + 255) / 256;
  constexpr int CG = NC / CPT;
  constexpr int RB = TR / 8;             // row swizzle span
  constexpr int CB = NC / 8;

  __shared__ float fT[KCH * TR];
  __shared__ float wT[KCH * NC];
  __shared__ int rIdx[TR];

  const int tid = threadIdx.x;
  int e, tile, kz;
  if (FLAT) {
    const int b = blockIdx.x;
    kz = b % SK;
    const int item = b / SK;
    if (item >= *nItems) return;  // dense tail exit only
    const int s = sched[item];
    e = s & 255;
    tile = s >> 8;
  } else {
    e = 0;
    tile = blockIdx.x;
    kz = blockIdx.z;
  }
  const int count = cnt ? cnt[e] : B_;

  if (tid < TR) {
    const int slot = tile * TR + tid;
    rIdx[tid] = (slot < count) ? (rowList ? rowList[e * B_ + slot] : slot) : 0;
  }
  __syncthreads();

  // loop-invariant staging constants -> registers
  unsigned grows[FITER];
  int dcf[FITER], sbf[FITER];
#pragma unroll
  for (int i = 0; i < FITER; ++i) {
    const int idx = i * 256 + tid;
    const int rl = idx / DCB;
    dcf[i] = idx % DCB;
    grows[i] = (unsigned)rIdx[rl];
    sbf[i] = (((rl >> 3) ^ (dcf[i] & (RB - 1))) << 3) + (rl & 7);
  }
  int wc[WITER], wdc[WITER], wsb[WITER];
  bool wact[WITER];
#pragma unroll
  for (int i = 0; i < WITER; ++i) {
    const int idx = i * 256 + tid;
    wact[i] = idx < WSLOTS;
    const int c = wact[i] ? (idx / DCB) : 0;
    wc[i] = c;
    wdc[i] = idx % DCB;
    wsb[i] = (((c >> 3) ^ (wdc[i] & (CB - 1))) << 3) + (c & 7);
  }

  const int cg = tid % CG;
  const int rg = tid / CG;

  float acc[RPT][CPT];
#pragma unroll
  for (int r = 0; r < RPT; ++r)
#pragma unroll
    for (int c = 0; c < CPT; ++c) acc[r][c] = 0.f;

  const float* We = Wall + (size_t)e * NC * D_;
  constexpr int KRANGE = D_ / SK;
  constexpr int NCH = KRANGE / KCH;
  const int k0 = kz * KRANGE;

  // prefetch chunk 0 into registers
  float4 pf[FITER], pw[WITER];
#pragma unroll
  for (int i = 0; i < FITER; ++i)
    pf[i] = *(const float4*)(feat + (size_t)grows[i] * D_ + k0 + dcf[i] * 4);
#pragma unroll
  for (int i = 0; i < WITER; ++i)
    if (wact[i])
      pw[i] = *(const float4*)(We + (size_t)wc[i] * D_ + k0 + wdc[i] * 4);

  for (int ch = 0; ch < NCH; ++ch) {
    // drain prefetch regs -> LDS (transposed + swizzled)
#pragma unroll
    for (int i = 0; i < FITER; ++i) {
      float* p = &fT[(dcf[i] * 4) * TR + sbf[i]];
      p[0 * TR] = pf[i].x;
      p[1 * TR] = pf[i].y;
      p[2 * TR] = pf[i].z;
      p[3 * TR] = pf[i].w;
    }
#pragma unroll
    for (int i = 0; i < WITER; ++i)
      if (wact[i]) {
        float* p = &wT[(wdc[i] * 4) * NC + wsb[i]];
        p[0 * NC] = pw[i].x;
        p[1 * NC] = pw[i].y;
        p[2 * NC] = pw[i].z;
        p[3 * NC] = pw[i].w;
      }
    __syncthreads();
    // issue next chunk's global loads early; they overlap the dd-loop
    if (ch + 1 < NCH) {
      const int kb = k0 + (ch + 1) * KCH;
#pragma unroll
      for (int i = 0; i < FITER; ++i)
        pf[i] = *(const float4*)(feat + (size_t)grows[i] * D_ + kb + dcf[i] * 4);
#pragma unroll
      for (int i = 0; i < WITER; ++i)
        if (wact[i])
          pw[i] = *(const float4*)(We + (size_t)wc[i] * D_ + kb + wdc[i] * 4);
    }
    // outer-product register tile
#pragma unroll
    for (int dd = 0; dd < KCH; ++dd) {
      const int sz = (dd >> 2) & (RB - 1);
      const int sw = (dd >> 2) & (CB - 1);
      float a[RPT], bb[CPT];
      if constexpr (RPT >= 4) {
#pragma unroll
        for (int r4 = 0; r4 < RPT / 4; ++r4) {
          const int col = rg * RPT + r4 * 4;
          const float4 v = *(
              const float4*)&fT[dd * TR + (((col >> 3) ^ sz) << 3) + (col & 7)];
          a[r4 * 4 + 0] = v.x;
          a[r4 * 4 + 1] = v.y;
          a[r4 * 4 + 2] = v.z;
          a[r4 * 4 + 3] = v.w;
        }
      } else {  // RPT == 2
        const int col = rg * 2;
        const float2 v =
            *(const float2*)&fT[dd * TR + (((col >> 3) ^ sz) << 3) + (col & 7)];
        a[0] = v.x;
        a[1] = v.y;
      }
      if constexpr (CPT >= 4) {
#pragma unroll
        for (int c4 = 0; c4 < CPT / 4; ++c4) {
          const int col = cg * CPT + c4 * 4;
          const float4 v = *(
              const float4*)&wT[dd * NC + (((col >> 3) ^ sw) << 3) + (col & 7)];
          bb[c4 * 4 + 0] = v.x;
          bb[c4 * 4 + 1] = v.y;
          bb[c4 * 4 + 2] = v.z;
          bb[c4 * 4 + 3] = v.w;
        }
      } else {  // CPT == 2
        const int col = cg * 2;
        const float2 v =
            *(const float2*)&wT[dd * NC + (((col >> 3) ^ sw) << 3) + (col & 7)];
        bb[0] = v.x;
        bb[1] = v.y;
      }
#pragma unroll
      for (int r = 0; r < RPT; ++r)
#pragma unroll
        for (int c = 0; c < CPT; ++c) acc[r][c] += a[r] * bb[c];
    }
    __syncthreads();
  }

  // epilogue: vector stores to this kz's partial slice
  float* pk = kz ? (partRest + (size_t)(kz - 1) * B_ * NC) : part0;
#pragma unroll
  for (int r = 0; r < RPT; ++r) {
    const int lrow = rg * RPT + r;
    const int slot = tile * TR + lrow;
    if (slot < count) {
      const int grow = rIdx[lrow];
      float* dst = pk + (size_t)grow * NC + cg * CPT;
      if constexpr (CPT >= 4) {
#pragma unroll
        for (int c4 = 0; c4 < CPT / 4; ++c4)
          *(float4*)(dst + c4 * 4) =
              make_float4(acc[r][c4 * 4 + 0], acc[r][c4 * 4 + 1],
                          acc[r][c4 * 4 + 2], acc[r][c4 * 4 + 3]);
      } else {
        *(float2*)dst = make_float2(acc[r][0], acc[r][1]);
      }
    }
  }
}

// Reduce coarse partials (fixed order => deterministic), add bias, argmax,
// write coarse_output + expert_id, build compacted row lists (block-aggregated
// atomics), and LAST block also builds the expert-GEMM (e,tile) schedule.
__global__ __launch_bounds__(256) void coarse_finish(
    const float* __restrict__ cpart0, const float* __restrict__ cpartRest,
    const float* __restrict__ cb, float* __restrict__ out0,
    float* __restrict__ out1, int* __restrict__ eidArr, int* __restrict__ cnt,
    int* __restrict__ done, int* __restrict__ rowList, int* __restrict__ sched,
    int* __restrict__ nItems) {
  __shared__ int lcnt[E_];
  __shared__ int lbase[E_];
  __shared__ int lastFlag;
  const int tid = threadIdx.x;
  if (tid < E_) lcnt[tid] = 0;
  if (tid == 0) lastFlag = 0;
  __syncthreads();
  const int row = blockIdx.x * 256 + tid;

  float v[E_];
#pragma unroll
  for (int j = 0; j < E_; ++j) v[j] = cb[j];
#pragma unroll
  for (int kz = 0; kz < SK_C; ++kz) {
    const float* p = (kz == 0) ? (cpart0 + (size_t)row * E_)
                               : (cpartRest + ((size_t)(kz - 1) * B_ + row) * E_);
#pragma unroll
    for (int j4 = 0; j4 < E_ / 4; ++j4) {
      const float4 t = *(const float4*)(p + j4 * 4);
      v[j4 * 4 + 0] += t.x;
      v[j4 * 4 + 1] += t.y;
      v[j4 * 4 + 2] += t.z;
      v[j4 * 4 + 3] += t.w;
    }
  }
  int best = 0;
  float bv = v[0];
#pragma unroll
  for (int j = 1; j < E_; ++j)
    if (v[j] > bv) {
      bv = v[j];
      best = j;
    }

  float* o0 = out0 + (size_t)row * E_;
#pragma unroll
  for (int j4 = 0; j4 < E_ / 4; ++j4)
    *(float4*)(o0 + j4 * 4) = make_float4(v[j4 * 4 + 0], v[j4 * 4 + 1],
                                          v[j4 * 4 + 2], v[j4 * 4 + 3]);
  out1[row] = (float)best;
  eidArr[row] = best;

  const int lpos = atomicAdd(&lcnt[best], 1);
  __syncthreads();
  if (tid < E_) lbase[tid] = atomicAdd(&cnt[tid], lcnt[tid]);
  __syncthreads();
  rowList[best * B_ + lbase[best] + lpos] = row;

  // last block builds the schedule (cnt is final once done==gridDim)
  __threadfence();
  if (tid == 0)
    if (atomicAdd(done, 1) == (int)gridDim.x - 1) lastFlag = 1;
  __syncthreads();
  if (lastFlag) {
    if (tid < E_) lcnt[tid] = (atomicAdd(&cnt[tid], 0) + TR_E - 1) / TR_E;
    __syncthreads();
    if (tid == 0) {
      int a = 0;
      for (int e = 0; e < E_; ++e) {
        lbase[e] = a;
        a += lcnt[e];
      }
      *nItems = a;
    }
    __syncthreads();
    if (tid < E_) {
      const int o = lbase[tid], n = lcnt[tid];
      for (int k = 0; k < n; ++k) sched[o + k] = tid | (k << 8);
    }
  }
}

// Wave-per-row: reduce y partials (fixed order), bias, softmax, argmax+start.
__global__ __launch_bounds__(256) void finish_rows(
    const float* __restrict__ ypart0, const float* __restrict__ ypartRest,
    const float* __restrict__ eb, const int* __restrict__ eidArr,
    float* __restrict__ out2, float* __restrict__ out3) {
  const int lane = threadIdx.x & 63;
  const int row = (blockIdx.x * 256 + threadIdx.x) >> 6;
  const int eid = eidArr[row];

  float v = eb[eid * C_ + lane];
  v += ypart0[(size_t)row * C_ + lane];
#pragma unroll
  for (int kz = 1; kz < SK_E; ++kz)
    v += ypartRest[((size_t)(kz - 1) * B_ + row) * C_ + lane];

  float m = v;
#pragma unroll
  for (int off = 32; off; off >>= 1) m = fmaxf(m, __shfl_xor(m, off));
  const float p = __expf(v - m);
  float s = p;
#pragma unroll
  for (int off = 32; off; off >>= 1) s += __shfl_xor(s, off);
  out2[(size_t)row * C_ + lane] = p / s;  // ypart0 aliases out2; read done

  float av = v;
  int ai = lane;
#pragma unroll
  for (int off = 32; off; off >>= 1) {
    const float ov = __shfl_xor(av, off);
    const int oi = __shfl_xor(ai, off);
    if (ov > av || (ov == av && oi < ai)) {
      av = ov;
      ai = oi;
    }
  }
  if (lane == 0) out3[row] = (float)(ai + (eid << 6));
}

extern "C" void kernel_launch(void* const* d_in, const int* in_sizes, int n_in,
                              void* d_out, int out_size, void* d_ws,
                              size_t ws_size, hipStream_t stream) {
  const float* feat = (const float*)d_in[0];  // [B, D]
  const float* cw = (const float*)d_in[1];    // [E, D]
  const float* cb = (const float*)d_in[2];    // [E]
  const float* ew = (const float*)d_in[3];    // [E, C, D]
  const float* eb = (const float*)d_in[4];    // [E, C]

  float* out0 = (float*)d_out;           // coarse_output [B, E]
  float* out1 = out0 + (size_t)B_ * E_;  // expert_id [B] (as float)
  float* out2 = out1 + B_;               // local_preds [B, C]
  float* out3 = out2 + (size_t)B_ * C_;  // global_preds [B]

  // ws (~21 MB): coarse kz>=1 partials, expert kz>=1 partials, routing
  // metadata. kz==0 slices alias output regions (same element, same thread).
  char* ws = (char*)d_ws;
  float* cpartRest = (float*)ws;                                 // 7*B*E
  float* ypartRest = cpartRest + (size_t)(SK_C - 1) * B_ * E_;   // 3*B*C
  int* rowList = (int*)(ypartRest + (size_t)(SK_E - 1) * B_ * C_);  // E*B
  int* cnt = rowList + (size_t)E_ * B_;  // 16 counts; done @ +16 (pad 64)
  int* done = cnt + E_;
  int* eidArr = cnt + 64;                // B
  int* sched = eidArr + B_;              // MAXITEMS (pad 512)
  int* nItems = sched + 512;             // 1

  hipMemsetAsync(cnt, 0, 256, stream);  // cnt[0..15] + done

  // 1) coarse GEMM: (256,1,8) = 2048 blocks, 10.5 KB LDS -> 32 waves/CU
  gemm_tile<2, 2, E_, TR_C, SK_C, 32, false>
      <<<dim3(B_ / TR_C, 1, SK_C), 256, 0, stream>>>(
          feat, cw, nullptr, nullptr, nullptr, nullptr, out0, cpartRest);
  // 2) reduce + argmax + compaction + schedule build (last block)
  coarse_finish<<<B_ / 256, 256, 0, stream>>>(out0, cpartRest, cb, out0, out1,
                                              eidArr, cnt, done, rowList,
                                              sched, nItems);
  // 3) expert GEMM over dense flat-scheduled grid; KCH=64 -> 8 barrier pairs
  gemm_tile<4, 4, C_, TR_E, SK_E, 64, true>
      <<<MAXITEMS * SK_E, 256, 0, stream>>>(feat, ew, rowList, cnt, sched,
                                            nItems, out2, ypartRest);
  // 4) softmax + argmax + class-range start
  finish_rows<<<(B_ * 64) / 256, 256, 0, stream>>>(out2, ypartRest, eb, eidArr,
                                                   out2, out3);
}